// Round 7
// baseline (415.298 us; speedup 1.0000x reference)
//
#include <hip/hip_runtime.h>
#include <hip/hip_cooperative_groups.h>

namespace cg = cooperative_groups;

#define D 128
#define BKT_SHIFT 9
#define BKT_SIZE 512
#define P1_EPB 4096
#define CNT_EPB 8192
#define SW_LDU 68     // uints per W row in LDS (136 ushorts = 128 + 8 pad)
#define COOP_G 256    // 1 block/CU -> co-residency guaranteed

typedef __attribute__((ext_vector_type(8))) short bf16x8;
typedef __attribute__((ext_vector_type(4))) float f32x4;

__device__ inline unsigned int pack2bf(float a, float b) {
    unsigned int ua = __float_as_uint(a);
    unsigned int ub = __float_as_uint(b);
    ua = (ua + 0x7fffu + ((ua >> 16) & 1u)) >> 16;   // RNE
    ub = (ub + 0x7fffu + ((ub >> 16) & 1u)) >> 16;
    return ua | (ub << 16);
}
__device__ inline unsigned short pack1bf(float a) {
    unsigned int ua = __float_as_uint(a);
    return (unsigned short)((ua + 0x7fffu + ((ua >> 16) & 1u)) >> 16);
}

union SMem {
    struct { int hcnt[256]; int hbase[256]; } c;                 // partition
    struct { int hist[BKT_SIZE]; int cur[BKT_SIZE]; int sb[256]; } d; // sort
    unsigned int sW[128 * SW_LDU];                               // gemm (34,816B)
};

// =====================================================================
// Cooperative mega-kernel: zero + bucket-count + scan + partition +
// per-bucket sort + gemm_z.  grid = COOP_G blocks x 256 thr.
// =====================================================================
__global__ __launch_bounds__(256) void build_all_kernel(
    const float* __restrict__ h, const int* __restrict__ esrc,
    const int* __restrict__ edst, const float* __restrict__ W,
    int* __restrict__ gstart, int* __restrict__ gend,
    int* __restrict__ bucketCnt, int* __restrict__ bucketBase,
    int* __restrict__ bucketCur, int* __restrict__ sorted_src,
    unsigned int* __restrict__ pairs, unsigned short* __restrict__ z,
    int n_nodes, int n_edges, int nbk)
{
    __shared__ SMem sm;
    cg::grid_group grid = cg::this_grid();
    const int tid = threadIdx.x;
    const int bid = blockIdx.x;
    const int G = gridDim.x;

    // ---- Phase A: zero global counts; LDS bucket histogram ----
    if (bid == 0 && tid < nbk) bucketCnt[tid] = 0;
    sm.c.hcnt[tid] = 0;
    __syncthreads();
    for (int e = bid * 256 + tid; e < n_edges; e += G * 256)
        atomicAdd(&sm.c.hcnt[edst[e] >> BKT_SHIFT], 1);
    __syncthreads();
    grid.sync();   // zeroing visible everywhere
    if (tid < nbk && sm.c.hcnt[tid] > 0) atomicAdd(&bucketCnt[tid], sm.c.hcnt[tid]);
    grid.sync();   // counts final

    // ---- Phase B: scan bucket counts (block 0) ----
    if (bid == 0) {
        int v = (tid < nbk) ? bucketCnt[tid] : 0;
        sm.d.sb[tid] = v;
        __syncthreads();
        #pragma unroll
        for (int off = 1; off < 256; off <<= 1) {
            int x = (tid >= off) ? sm.d.sb[tid - off] : 0;
            __syncthreads();
            sm.d.sb[tid] += x;
            __syncthreads();
        }
        if (tid < nbk) {
            int base = sm.d.sb[tid] - v;
            bucketBase[tid] = base;
            bucketCur[tid] = base;
        }
    }
    grid.sync();

    // ---- Phase C: partition edges into buckets, packed (src<<9)|local ----
    const int nchunks = (n_edges + P1_EPB - 1) / P1_EPB;
    for (int chunk = bid; chunk < nchunks; chunk += G) {
        const int base = chunk * P1_EPB;
        sm.c.hcnt[tid] = 0;
        __syncthreads();
        unsigned int pk[16]; int bk[16];
        #pragma unroll
        for (int k = 0; k < 16; k++) {
            int e = base + k * 256 + tid;
            if (e < n_edges) {
                int sv = esrc[e], dv = edst[e];
                bk[k] = dv >> BKT_SHIFT;
                pk[k] = ((unsigned)sv << BKT_SHIFT) | (unsigned)(dv & (BKT_SIZE - 1));
                atomicAdd(&sm.c.hcnt[bk[k]], 1);
            } else bk[k] = -1;
        }
        __syncthreads();
        int cval = sm.c.hcnt[tid];
        if (cval > 0) sm.c.hbase[tid] = atomicAdd(&bucketCur[tid], cval);
        __syncthreads();
        sm.c.hcnt[tid] = 0;   // reuse as local cursor
        __syncthreads();
        #pragma unroll
        for (int k = 0; k < 16; k++) {
            if (bk[k] >= 0) {
                int loc = atomicAdd(&sm.c.hcnt[bk[k]], 1);
                pairs[sm.c.hbase[bk[k]] + loc] = pk[k];
            }
        }
        __syncthreads();
    }
    grid.sync();   // pairs complete

    // ---- Phase D: per-bucket sort -> gstart/gend + sorted_src ----
    for (int bkt = bid; bkt < nbk; bkt += G) {
        const int nbase = bkt << BKT_SHIFT;
        const int pstart = bucketBase[bkt];
        const int pend = (bkt == nbk - 1) ? n_edges : bucketBase[bkt + 1];
        sm.d.hist[tid] = 0; sm.d.hist[tid + 256] = 0;
        __syncthreads();
        for (int j = pstart + tid; j < pend; j += 256)
            atomicAdd(&sm.d.hist[pairs[j] & (BKT_SIZE - 1)], 1);
        __syncthreads();
        int a  = sm.d.hist[2 * tid];
        int b2 = sm.d.hist[2 * tid + 1];
        int psum = a + b2;
        sm.d.sb[tid] = psum;
        __syncthreads();
        #pragma unroll
        for (int off = 1; off < 256; off <<= 1) {
            int x = (tid >= off) ? sm.d.sb[tid - off] : 0;
            __syncthreads();
            sm.d.sb[tid] += x;
            __syncthreads();
        }
        int pexcl = sm.d.sb[tid] - psum;
        sm.d.cur[2 * tid] = pexcl;
        sm.d.cur[2 * tid + 1] = pexcl + a;
        __syncthreads();
        for (int i = tid; i < BKT_SIZE; i += 256) {
            int nd = nbase + i;
            if (nd < n_nodes) {
                int st = pstart + sm.d.cur[i];
                gstart[nd] = st;
                gend[nd] = st + sm.d.hist[i];
            }
        }
        __syncthreads();
        for (int j = pstart + tid; j < pend; j += 256) {
            unsigned int p = pairs[j];
            int local = p & (BKT_SIZE - 1);
            int pos = pstart + atomicAdd(&sm.d.cur[local], 1);
            sorted_src[pos] = (int)(p >> BKT_SHIFT);
        }
        __syncthreads();
    }
    grid.sync();   // sorted_src done; pairs dead -> safe to overwrite as z

    // ---- Phase E: z = bf16(h @ W^T), grid-stride over 64-row tiles ----
    for (int i = tid; i < 4096; i += 256) {
        float4 w = ((const float4*)W)[i];
        int row = i >> 5, c4 = i & 31;
        unsigned int* dst = &sm.sW[row * SW_LDU + c4 * 2];
        dst[0] = pack2bf(w.x, w.y);
        dst[1] = pack2bf(w.z, w.w);
    }
    __syncthreads();
    const int wave = tid >> 6;
    const int lane = tid & 63;
    const int m = lane & 15;
    const int q = lane >> 4;
    const int ntiles = (n_nodes + 63) / 64;
    for (int tile = bid; tile < ntiles; tile += G) {
        const int r0 = tile * 64 + wave * 16;
        const int arow = r0 + m;
        const bool rvalid = arow < n_nodes;
        bf16x8 afrag[4];
        #pragma unroll
        for (int ks = 0; ks < 4; ks++) {
            float4 x = make_float4(0.f, 0.f, 0.f, 0.f), y = x;
            if (rvalid) {
                const float4* p = (const float4*)(h + (size_t)arow * D + ks * 32 + q * 8);
                x = p[0]; y = p[1];
            }
            union { unsigned int u[4]; bf16x8 v; } cvt;
            cvt.u[0] = pack2bf(x.x, x.y);
            cvt.u[1] = pack2bf(x.z, x.w);
            cvt.u[2] = pack2bf(y.x, y.y);
            cvt.u[3] = pack2bf(y.z, y.w);
            afrag[ks] = cvt.v;
        }
        f32x4 acc[8];
        #pragma unroll
        for (int ct = 0; ct < 8; ct++) acc[ct] = (f32x4){0.f, 0.f, 0.f, 0.f};
        #pragma unroll
        for (int ct = 0; ct < 8; ct++) {
            #pragma unroll
            for (int ks = 0; ks < 4; ks++) {
                const unsigned int* p = &sm.sW[(ct * 16 + m) * SW_LDU + ks * 16 + q * 4];
                union { uint4 u; bf16x8 v; } bu;
                bu.u = *(const uint4*)p;
                acc[ct] = __builtin_amdgcn_mfma_f32_16x16x32_bf16(afrag[ks], bu.v, acc[ct], 0, 0, 0);
            }
        }
        #pragma unroll
        for (int ct = 0; ct < 8; ct++) {
            int col = ct * 16 + m;
            #pragma unroll
            for (int i = 0; i < 4; i++) {
                int r = r0 + q * 4 + i;
                if (r < n_nodes) z[(size_t)r * D + col] = pack1bf(acc[ct][i]);
            }
        }
    }
}

// ================= full-row gather + bias + relu (round-5 shape) =========
// 32 lanes per node (lane -> uint2 = 4 bf16 of the 256B row); 8 nodes/block.
__global__ __launch_bounds__(256) void gather_row_kernel(
    const unsigned short* __restrict__ z, const int* __restrict__ gstart,
    const int* __restrict__ gend, const int* __restrict__ sorted_src,
    const float* __restrict__ b, float* __restrict__ out, int n_nodes)
{
    const int tid = threadIdx.x;
    const int node = blockIdx.x * 8 + (tid >> 5);
    const int lane = tid & 31;
    if (node >= n_nodes) return;
    int e = gstart[node];
    const int end = gend[node];
    const uint2* __restrict__ z2 = (const uint2*)z;   // 32 uint2 per row
    float4 acc = make_float4(0.f, 0.f, 0.f, 0.f);
    for (; e + 4 <= end; e += 4) {
        int s0 = sorted_src[e + 0];
        int s1 = sorted_src[e + 1];
        int s2 = sorted_src[e + 2];
        int s3 = sorted_src[e + 3];
        uint2 v0 = z2[(size_t)s0 * 32 + lane];
        uint2 v1 = z2[(size_t)s1 * 32 + lane];
        uint2 v2 = z2[(size_t)s2 * 32 + lane];
        uint2 v3 = z2[(size_t)s3 * 32 + lane];
        acc.x += __uint_as_float(v0.x << 16) + __uint_as_float(v1.x << 16)
               + __uint_as_float(v2.x << 16) + __uint_as_float(v3.x << 16);
        acc.y += __uint_as_float(v0.x & 0xffff0000u) + __uint_as_float(v1.x & 0xffff0000u)
               + __uint_as_float(v2.x & 0xffff0000u) + __uint_as_float(v3.x & 0xffff0000u);
        acc.z += __uint_as_float(v0.y << 16) + __uint_as_float(v1.y << 16)
               + __uint_as_float(v2.y << 16) + __uint_as_float(v3.y << 16);
        acc.w += __uint_as_float(v0.y & 0xffff0000u) + __uint_as_float(v1.y & 0xffff0000u)
               + __uint_as_float(v2.y & 0xffff0000u) + __uint_as_float(v3.y & 0xffff0000u);
    }
    for (; e < end; e++) {
        uint2 v = z2[(size_t)sorted_src[e] * 32 + lane];
        acc.x += __uint_as_float(v.x << 16);
        acc.y += __uint_as_float(v.x & 0xffff0000u);
        acc.z += __uint_as_float(v.y << 16);
        acc.w += __uint_as_float(v.y & 0xffff0000u);
    }
    float4 bb = ((const float4*)b)[lane];   // cols lane*4 .. +3
    float vx = acc.x + bb.x, vy = acc.y + bb.y;
    float vz = acc.z + bb.z, vw = acc.w + bb.w;
    ((float4*)out)[(size_t)node * 32 + lane] = make_float4(
        vx > 0.f ? vx : 0.f, vy > 0.f ? vy : 0.f,
        vz > 0.f ? vz : 0.f, vw > 0.f ? vw : 0.f);
}

// ============ separate-kernel fallback (round-6 path, coop rejected) ======

__global__ __launch_bounds__(256) void bucket_count_kernel(
    const int* __restrict__ edst, int* __restrict__ bucketCnt, int n_edges, int nbk)
{
    __shared__ int hcnt[256];
    const int tid = threadIdx.x;
    hcnt[tid] = 0;
    __syncthreads();
    const int base = blockIdx.x * CNT_EPB;
    const int lim = min(CNT_EPB, n_edges - base);
    for (int k = tid; k < lim; k += 256)
        atomicAdd(&hcnt[edst[base + k] >> BKT_SHIFT], 1);
    __syncthreads();
    if (tid < nbk && hcnt[tid] > 0) atomicAdd(&bucketCnt[tid], hcnt[tid]);
}

__global__ __launch_bounds__(256) void bucket_scan_kernel(
    const int* __restrict__ bucketCnt, int* __restrict__ bucketBase,
    int* __restrict__ bucketCur, int nbk)
{
    __shared__ int s[256];
    const int t = threadIdx.x;
    int v = (t < nbk) ? bucketCnt[t] : 0;
    s[t] = v;
    __syncthreads();
    #pragma unroll
    for (int off = 1; off < 256; off <<= 1) {
        int x = (t >= off) ? s[t - off] : 0;
        __syncthreads();
        s[t] += x;
        __syncthreads();
    }
    if (t < nbk) {
        int base = s[t] - v;
        bucketBase[t] = base;
        bucketCur[t] = base;
    }
}

__global__ __launch_bounds__(256) void p1_partition_kernel(
    const int* __restrict__ esrc, const int* __restrict__ edst,
    int* __restrict__ bucketCur, unsigned int* __restrict__ pairs, int n_edges)
{
    __shared__ int hcnt[256];
    __shared__ int hbase[256];
    const int tid = threadIdx.x;
    const int base = blockIdx.x * P1_EPB;
    hcnt[tid] = 0;
    __syncthreads();
    unsigned int pk[16]; int bk[16];
    #pragma unroll
    for (int k = 0; k < 16; k++) {
        int e = base + k * 256 + tid;
        if (e < n_edges) {
            int sv = esrc[e], dv = edst[e];
            bk[k] = dv >> BKT_SHIFT;
            pk[k] = ((unsigned)sv << BKT_SHIFT) | (unsigned)(dv & (BKT_SIZE - 1));
            atomicAdd(&hcnt[bk[k]], 1);
        } else bk[k] = -1;
    }
    __syncthreads();
    int cval = hcnt[tid];
    if (cval > 0) hbase[tid] = atomicAdd(&bucketCur[tid], cval);
    __syncthreads();
    hcnt[tid] = 0;
    __syncthreads();
    #pragma unroll
    for (int k = 0; k < 16; k++) {
        if (bk[k] >= 0) {
            int loc = atomicAdd(&hcnt[bk[k]], 1);
            pairs[hbase[bk[k]] + loc] = pk[k];
        }
    }
}

__global__ __launch_bounds__(256) void p2_sort_kernel(
    const unsigned int* __restrict__ pairs, const int* __restrict__ bucketBase,
    int* __restrict__ sorted_src, int* __restrict__ gstart, int* __restrict__ gend,
    int n_nodes, int n_edges, int nbk)
{
    __shared__ int hist[BKT_SIZE];
    __shared__ int cur[BKT_SIZE];
    __shared__ int sb[256];
    const int tid = threadIdx.x;
    const int bkt = blockIdx.x;
    const int nbase = bkt << BKT_SHIFT;
    const int pstart = bucketBase[bkt];
    const int pend = (bkt == nbk - 1) ? n_edges : bucketBase[bkt + 1];
    hist[tid] = 0; hist[tid + 256] = 0;
    __syncthreads();
    for (int j = pstart + tid; j < pend; j += 256)
        atomicAdd(&hist[pairs[j] & (BKT_SIZE - 1)], 1);
    __syncthreads();
    int a  = hist[2 * tid];
    int b2 = hist[2 * tid + 1];
    int psum = a + b2;
    sb[tid] = psum;
    __syncthreads();
    #pragma unroll
    for (int off = 1; off < 256; off <<= 1) {
        int x = (tid >= off) ? sb[tid - off] : 0;
        __syncthreads();
        sb[tid] += x;
        __syncthreads();
    }
    int pexcl = sb[tid] - psum;
    cur[2 * tid] = pexcl;
    cur[2 * tid + 1] = pexcl + a;
    __syncthreads();
    for (int i = tid; i < BKT_SIZE; i += 256) {
        int nd = nbase + i;
        if (nd < n_nodes) {
            int st = pstart + cur[i];
            gstart[nd] = st;
            gend[nd] = st + hist[i];
        }
    }
    __syncthreads();
    for (int j = pstart + tid; j < pend; j += 256) {
        unsigned int p = pairs[j];
        int local = p & (BKT_SIZE - 1);
        int pos = pstart + atomicAdd(&cur[local], 1);
        sorted_src[pos] = (int)(p >> BKT_SHIFT);
    }
}

__global__ __launch_bounds__(256) void gemm_z_kernel(
    const float* __restrict__ h, const float* __restrict__ W,
    unsigned short* __restrict__ z, int n_nodes)
{
    __shared__ unsigned int sW[128 * SW_LDU];
    const int tid = threadIdx.x;
    for (int i = tid; i < 4096; i += 256) {
        float4 w = ((const float4*)W)[i];
        int row = i >> 5, c4 = i & 31;
        unsigned int* dst = &sW[row * SW_LDU + c4 * 2];
        dst[0] = pack2bf(w.x, w.y);
        dst[1] = pack2bf(w.z, w.w);
    }
    __syncthreads();
    const int wave = tid >> 6;
    const int lane = tid & 63;
    const int m = lane & 15;
    const int q = lane >> 4;
    const int r0 = blockIdx.x * 64 + wave * 16;
    const int arow = r0 + m;
    const bool rvalid = arow < n_nodes;
    bf16x8 afrag[4];
    #pragma unroll
    for (int ks = 0; ks < 4; ks++) {
        float4 x = make_float4(0.f, 0.f, 0.f, 0.f), y = x;
        if (rvalid) {
            const float4* p = (const float4*)(h + (size_t)arow * D + ks * 32 + q * 8);
            x = p[0]; y = p[1];
        }
        union { unsigned int u[4]; bf16x8 v; } cvt;
        cvt.u[0] = pack2bf(x.x, x.y);
        cvt.u[1] = pack2bf(x.z, x.w);
        cvt.u[2] = pack2bf(y.x, y.y);
        cvt.u[3] = pack2bf(y.z, y.w);
        afrag[ks] = cvt.v;
    }
    f32x4 acc[8];
    #pragma unroll
    for (int ct = 0; ct < 8; ct++) acc[ct] = (f32x4){0.f, 0.f, 0.f, 0.f};
    #pragma unroll
    for (int ct = 0; ct < 8; ct++) {
        #pragma unroll
        for (int ks = 0; ks < 4; ks++) {
            const unsigned int* p = &sW[(ct * 16 + m) * SW_LDU + ks * 16 + q * 4];
            union { uint4 u; bf16x8 v; } bu;
            bu.u = *(const uint4*)p;
            acc[ct] = __builtin_amdgcn_mfma_f32_16x16x32_bf16(afrag[ks], bu.v, acc[ct], 0, 0, 0);
        }
    }
    #pragma unroll
    for (int ct = 0; ct < 8; ct++) {
        int col = ct * 16 + m;
        #pragma unroll
        for (int i = 0; i < 4; i++) {
            int r = r0 + q * 4 + i;
            if (r < n_nodes) z[(size_t)r * D + col] = pack1bf(acc[ct][i]);
        }
    }
}

// ============ last-resort fallback (tiny ws): atomic scatter + gemm =======

__global__ __launch_bounds__(256) void scatter_kernel(
    const float* __restrict__ h, const int* __restrict__ esrc,
    const int* __restrict__ edst, float* __restrict__ out, int n_edges)
{
    int gid = blockIdx.x * 256 + threadIdx.x;
    int e = gid >> 5;
    int l = gid & 31;
    if (e >= n_edges) return;
    int s = esrc[e];
    int d = edst[e];
    float4 v = ((const float4*)(h + (size_t)s * D))[l];
    float* o = out + (size_t)d * D + (size_t)l * 4;
    atomicAdd(o + 0, v.x);
    atomicAdd(o + 1, v.y);
    atomicAdd(o + 2, v.z);
    atomicAdd(o + 3, v.w);
}

__global__ __launch_bounds__(256) void mfma_gemm_relu_kernel(
    float* __restrict__ io, const float* __restrict__ W,
    const float* __restrict__ b, int n_nodes)
{
    __shared__ unsigned int sW[128 * SW_LDU];
    const int tid = threadIdx.x;
    for (int i = tid; i < 4096; i += 256) {
        float4 w = ((const float4*)W)[i];
        int row = i >> 5, c4 = i & 31;
        unsigned int* dst = &sW[row * SW_LDU + c4 * 2];
        dst[0] = pack2bf(w.x, w.y);
        dst[1] = pack2bf(w.z, w.w);
    }
    __syncthreads();
    const int wave = tid >> 6;
    const int lane = tid & 63;
    const int m = lane & 15;
    const int q = lane >> 4;
    const int r0 = blockIdx.x * 64 + wave * 16;
    const int arow = r0 + m;
    const bool rvalid = arow < n_nodes;
    bf16x8 afrag[4];
    #pragma unroll
    for (int ks = 0; ks < 4; ks++) {
        float4 x = make_float4(0.f, 0.f, 0.f, 0.f), y = x;
        if (rvalid) {
            const float4* p = (const float4*)(io + (size_t)arow * D + ks * 32 + q * 8);
            x = p[0]; y = p[1];
        }
        union { unsigned int u[4]; bf16x8 v; } cvt;
        cvt.u[0] = pack2bf(x.x, x.y);
        cvt.u[1] = pack2bf(x.z, x.w);
        cvt.u[2] = pack2bf(y.x, y.y);
        cvt.u[3] = pack2bf(y.z, y.w);
        afrag[ks] = cvt.v;
    }
    f32x4 acc[8];
    #pragma unroll
    for (int ct = 0; ct < 8; ct++) acc[ct] = (f32x4){0.f, 0.f, 0.f, 0.f};
    #pragma unroll
    for (int ct = 0; ct < 8; ct++) {
        #pragma unroll
        for (int ks = 0; ks < 4; ks++) {
            const unsigned int* p = &sW[(ct * 16 + m) * SW_LDU + ks * 16 + q * 4];
            union { uint4 u; bf16x8 v; } bu;
            bu.u = *(const uint4*)p;
            acc[ct] = __builtin_amdgcn_mfma_f32_16x16x32_bf16(afrag[ks], bu.v, acc[ct], 0, 0, 0);
        }
    }
    #pragma unroll
    for (int ct = 0; ct < 8; ct++) {
        int col = ct * 16 + m;
        float bias = b[col];
        #pragma unroll
        for (int i = 0; i < 4; i++) {
            int r = r0 + q * 4 + i;
            if (r < n_nodes) {
                float v = acc[ct][i] + bias;
                io[(size_t)r * D + col] = v > 0.f ? v : 0.f;
            }
        }
    }
}

extern "C" void kernel_launch(void* const* d_in, const int* in_sizes, int n_in,
                              void* d_out, int out_size, void* d_ws, size_t ws_size,
                              hipStream_t stream) {
    const float* h    = (const float*)d_in[0];
    const int*   esrc = (const int*)d_in[1];
    const int*   edst = (const int*)d_in[2];
    const float* W    = (const float*)d_in[3];
    const float* b    = (const float*)d_in[4];
    float* out = (float*)d_out;
    const int n_nodes = in_sizes[0] / D;
    const int n_edges = in_sizes[1];
    const int NBK = (n_nodes + BKT_SIZE - 1) / BKT_SIZE;

    size_t zone_bytes = (size_t)n_edges * 4;                 // packed pairs
    size_t zb2 = (size_t)n_nodes * D * 2;                    // z (bf16)
    if (zb2 > zone_bytes) zone_bytes = zb2;
    size_t fixed = ((size_t)2 * n_nodes + 3 * NBK + (size_t)n_edges) * 4;
    size_t zone_off = (fixed + 15) & ~(size_t)15;
    size_t need_main = zone_off + zone_bytes;

    if (ws_size >= need_main && NBK <= 256 && n_nodes <= (1 << 23)) {
        int* gstart     = (int*)d_ws;               // n_nodes
        int* gend       = gstart + n_nodes;         // n_nodes
        int* bucketCnt  = gend + n_nodes;           // NBK
        int* bucketBase = bucketCnt + NBK;          // NBK
        int* bucketCur  = bucketBase + NBK;         // NBK
        int* sorted_src = bucketCur + NBK;          // n_edges
        void* zone = (char*)d_ws + zone_off;
        unsigned int* pairs = (unsigned int*)zone;
        unsigned short* z = (unsigned short*)zone;  // aliases pairs (sequential use)

        void* kargs[] = {
            (void*)&h, (void*)&esrc, (void*)&edst, (void*)&W,
            (void*)&gstart, (void*)&gend,
            (void*)&bucketCnt, (void*)&bucketBase, (void*)&bucketCur,
            (void*)&sorted_src, (void*)&pairs, (void*)&z,
            (void*)&n_nodes, (void*)&n_edges, (void*)&NBK
        };
        hipError_t cerr = hipLaunchCooperativeKernel(
            (void*)build_all_kernel, dim3(COOP_G), dim3(256), kargs, 0, stream);
        if (cerr != hipSuccess) {
            // multi-kernel fallback (same buffers, same result)
            hipMemsetAsync(bucketCnt, 0, (size_t)NBK * sizeof(int), stream);
            bucket_count_kernel<<<(n_edges + CNT_EPB - 1) / CNT_EPB, 256, 0, stream>>>(
                edst, bucketCnt, n_edges, NBK);
            bucket_scan_kernel<<<1, 256, 0, stream>>>(bucketCnt, bucketBase, bucketCur, NBK);
            p1_partition_kernel<<<(n_edges + P1_EPB - 1) / P1_EPB, 256, 0, stream>>>(
                esrc, edst, bucketCur, pairs, n_edges);
            p2_sort_kernel<<<NBK, 256, 0, stream>>>(
                pairs, bucketBase, sorted_src, gstart, gend, n_nodes, n_edges, NBK);
            gemm_z_kernel<<<(n_nodes + 63) / 64, 256, 0, stream>>>(h, W, z, n_nodes);
        }
        gather_row_kernel<<<(n_nodes + 7) / 8, 256, 0, stream>>>(
            z, gstart, gend, sorted_src, b, out, n_nodes);
        return;
    }

    // last resort: fp32 atomic scatter + in-place mfma gemm
    hipMemsetAsync(out, 0, (size_t)n_nodes * D * sizeof(float), stream);
    long long total = (long long)n_edges * 32;
    scatter_kernel<<<(int)((total + 255) / 256), 256, 0, stream>>>(h, esrc, edst, out, n_edges);
    mfma_gemm_relu_kernel<<<(n_nodes + 63) / 64, 256, 0, stream>>>(out, W, b, n_nodes);
}